// Round 13
// baseline (260.951 us; speedup 1.0000x reference)
//
#include <hip/hip_runtime.h>

#define THREADS 256
#define CAP 128

typedef float floatx4 __attribute__((ext_vector_type(4)));

// ---------------- phase 0: zero row counters ----------------

__global__ void zero_kernel(int* __restrict__ p, int n) {
    int i = blockIdx.x * blockDim.x + threadIdx.x;
    if (i < n) p[i] = 0;
}

// ---------------- phase 1 (merged): ELL scatter  ||  gemm0 ----------------

__global__ void build_and_gemm0_kernel(const int* __restrict__ row, const int* __restrict__ col,
                                       const float* __restrict__ val, int* __restrict__ nxt,
                                       int* __restrict__ ell_c, float* __restrict__ ell_v, int E,
                                       const float* __restrict__ X, const float* __restrict__ W0,
                                       float* __restrict__ Y, int n, int K, int gridE) {
    if ((int)blockIdx.x < gridE) {
        int e = blockIdx.x * THREADS + threadIdx.x;
        if (e < E) {
            int r = row[e];
            int p = atomicAdd(&nxt[r], 1);
            if (p < CAP) {
                ell_c[r * CAP + p] = col[e];
                ell_v[r * CAP + p] = val[e];
            }
        }
    } else {
        int idx = (blockIdx.x - gridE) * THREADS + threadIdx.x;
        int r = idx >> 5;
        int f = idx & 31;
        if (r >= n) return;
        const float* xr = X + (size_t)r * K;
        float acc = 0.f;
        for (int k = 0; k < K; k += 4) {
            floatx4 x = *reinterpret_cast<const floatx4*>(xr + k);
            acc = fmaf(x.x, W0[(k + 0) * 32 + f], acc);
            acc = fmaf(x.y, W0[(k + 1) * 32 + f], acc);
            acc = fmaf(x.z, W0[(k + 2) * 32 + f], acc);
            acc = fmaf(x.w, W0[(k + 3) * 32 + f], acc);
        }
        Y[r * 32 + f] = acc;
    }
}

// ---------------- fused SpMM(+relu) + 32xFOUT GEMM ----------------
// One wave64 per row: lanes 0-31 / 32-63 process disjoint halves of the edge
// list with the same feature f; halves combine via shfl_xor(.,32). Halves the
// per-row serial gather chain vs 32-lane groups.

template <int FOUT>
__global__ void fused_spmm_gemm_kernel(const int* __restrict__ nxt, const int* __restrict__ ell_c,
                                       const float* __restrict__ ell_v, const float* __restrict__ Yin,
                                       const float* __restrict__ W, float* __restrict__ Yout, int n) {
    __shared__ float w[32 * FOUT];
    const int t = threadIdx.x;
    for (int i = t; i < 32 * FOUT; i += THREADS) w[i] = W[i];
    __syncthreads();

    int g = (blockIdx.x * THREADS + t) >> 6;   // one wave64 per row
    if (g >= n) return;
    const int f = t & 31;
    const int half = (t >> 5) & 1;
    int deg = min(nxt[g], CAP);
    int base = g * CAP;
    int mid = ((deg >> 1) + 3) & ~3;           // 4-aligned split keeps 16B loads aligned
    if (mid > deg) mid = deg;
    const int s = half ? mid : 0;
    const int e = half ? deg : mid;
    float acc = 0.f;
    int i = s;
    for (; i + 8 <= e; i += 8) {
        int4    cc0 = *reinterpret_cast<const int4*>(ell_c + base + i);
        int4    cc1 = *reinterpret_cast<const int4*>(ell_c + base + i + 4);
        floatx4 vv0 = *reinterpret_cast<const floatx4*>(ell_v + base + i);
        floatx4 vv1 = *reinterpret_cast<const floatx4*>(ell_v + base + i + 4);
        float y0 = Yin[(size_t)cc0.x * 32 + f];
        float y1 = Yin[(size_t)cc0.y * 32 + f];
        float y2 = Yin[(size_t)cc0.z * 32 + f];
        float y3 = Yin[(size_t)cc0.w * 32 + f];
        float y4 = Yin[(size_t)cc1.x * 32 + f];
        float y5 = Yin[(size_t)cc1.y * 32 + f];
        float y6 = Yin[(size_t)cc1.z * 32 + f];
        float y7 = Yin[(size_t)cc1.w * 32 + f];
        acc = fmaf(vv0.x, y0, acc);
        acc = fmaf(vv0.y, y1, acc);
        acc = fmaf(vv0.z, y2, acc);
        acc = fmaf(vv0.w, y3, acc);
        acc = fmaf(vv1.x, y4, acc);
        acc = fmaf(vv1.y, y5, acc);
        acc = fmaf(vv1.z, y6, acc);
        acc = fmaf(vv1.w, y7, acc);
    }
    for (; i + 4 <= e; i += 4) {
        int4    cc = *reinterpret_cast<const int4*>(ell_c + base + i);
        floatx4 vv = *reinterpret_cast<const floatx4*>(ell_v + base + i);
        acc = fmaf(vv.x, Yin[(size_t)cc.x * 32 + f], acc);
        acc = fmaf(vv.y, Yin[(size_t)cc.y * 32 + f], acc);
        acc = fmaf(vv.z, Yin[(size_t)cc.z * 32 + f], acc);
        acc = fmaf(vv.w, Yin[(size_t)cc.w * 32 + f], acc);
    }
    for (; i < e; ++i)
        acc = fmaf(ell_v[base + i], Yin[(size_t)ell_c[base + i] * 32 + f], acc);

    acc += __shfl_xor(acc, 32);                // combine halves
    float h = fmaxf(acc, 0.f);

    const int fo = f & (FOUT - 1);
    float y = 0.f;
#pragma unroll
    for (int k = 0; k < 32; ++k)
        y = fmaf(__shfl(h, k, 32), w[k * FOUT + fo], y);
    if (half == 0 && f < FOUT) Yout[(size_t)g * FOUT + f] = y;
}

// final z = A @ Y16 (no relu); 32 lanes per row split in two 16-lane halves
__global__ void spmm16_kernel(const int* __restrict__ nxt, const int* __restrict__ ell_c,
                              const float* __restrict__ ell_v, const float* __restrict__ Yin,
                              float* __restrict__ Z, int n) {
    int g = (blockIdx.x * blockDim.x + threadIdx.x) >> 5;
    if (g >= n) return;
    const int f = threadIdx.x & 15;
    const int half = (threadIdx.x >> 4) & 1;
    int deg = min(nxt[g], CAP);
    int base = g * CAP;
    int mid = ((deg >> 1) + 3) & ~3;
    if (mid > deg) mid = deg;
    const int s = half ? mid : 0;
    const int e = half ? deg : mid;
    float acc = 0.f;
    int i = s;
    for (; i + 8 <= e; i += 8) {
        int4    cc0 = *reinterpret_cast<const int4*>(ell_c + base + i);
        int4    cc1 = *reinterpret_cast<const int4*>(ell_c + base + i + 4);
        floatx4 vv0 = *reinterpret_cast<const floatx4*>(ell_v + base + i);
        floatx4 vv1 = *reinterpret_cast<const floatx4*>(ell_v + base + i + 4);
        acc = fmaf(vv0.x, Yin[(size_t)cc0.x * 16 + f], acc);
        acc = fmaf(vv0.y, Yin[(size_t)cc0.y * 16 + f], acc);
        acc = fmaf(vv0.z, Yin[(size_t)cc0.z * 16 + f], acc);
        acc = fmaf(vv0.w, Yin[(size_t)cc0.w * 16 + f], acc);
        acc = fmaf(vv1.x, Yin[(size_t)cc1.x * 16 + f], acc);
        acc = fmaf(vv1.y, Yin[(size_t)cc1.y * 16 + f], acc);
        acc = fmaf(vv1.z, Yin[(size_t)cc1.z * 16 + f], acc);
        acc = fmaf(vv1.w, Yin[(size_t)cc1.w * 16 + f], acc);
    }
    for (; i + 4 <= e; i += 4) {
        int4    cc = *reinterpret_cast<const int4*>(ell_c + base + i);
        floatx4 vv = *reinterpret_cast<const floatx4*>(ell_v + base + i);
        acc = fmaf(vv.x, Yin[(size_t)cc.x * 16 + f], acc);
        acc = fmaf(vv.y, Yin[(size_t)cc.y * 16 + f], acc);
        acc = fmaf(vv.z, Yin[(size_t)cc.z * 16 + f], acc);
        acc = fmaf(vv.w, Yin[(size_t)cc.w * 16 + f], acc);
    }
    for (; i < e; ++i)
        acc = fmaf(ell_v[base + i], Yin[(size_t)ell_c[base + i] * 16 + f], acc);

    acc += __shfl_xor(acc, 16, 32);
    if (half == 0) Z[(size_t)g * 16 + f] = acc;
}

// ---------------- z @ z^T (unchanged; nt stores proven -18us) ----------------

__global__ void zzt_kernel(const float* __restrict__ z, float* __restrict__ out, int n) {
    __shared__ float zi[32][16];
    const int t = threadIdx.x;
    const int bi = blockIdx.y * 32;
    for (int i = t; i < 512; i += THREADS) {
        int r = i >> 4, c = i & 15;
        zi[r][c] = (bi + r < n) ? z[(size_t)(bi + r) * 16 + c] : 0.f;
    }
    __syncthreads();
    int j0 = blockIdx.x * 1024 + t * 4;
    if (j0 >= n) return;
    float zj[4][16];
#pragma unroll
    for (int jj = 0; jj < 4; ++jj) {
#pragma unroll
        for (int k = 0; k < 16; k += 4) {
            floatx4 v = *reinterpret_cast<const floatx4*>(z + (size_t)(j0 + jj) * 16 + k);
            zj[jj][k] = v.x; zj[jj][k + 1] = v.y; zj[jj][k + 2] = v.z; zj[jj][k + 3] = v.w;
        }
    }
#pragma unroll 4
    for (int i = 0; i < 32; ++i) {
        if (bi + i >= n) break;
        floatx4 o = {0.f, 0.f, 0.f, 0.f};
#pragma unroll
        for (int k = 0; k < 16; ++k) {
            float a = zi[i][k];
            o.x = fmaf(a, zj[0][k], o.x);
            o.y = fmaf(a, zj[1][k], o.y);
            o.z = fmaf(a, zj[2][k], o.z);
            o.w = fmaf(a, zj[3][k], o.w);
        }
        __builtin_nontemporal_store(o, reinterpret_cast<floatx4*>(out + (size_t)(bi + i) * n + j0));
    }
}

// ---------------- launch ----------------

extern "C" void kernel_launch(void* const* d_in, const int* in_sizes, int n_in,
                              void* d_out, int out_size, void* d_ws, size_t ws_size,
                              hipStream_t stream) {
    const float* features = (const float*)d_in[0];
    const int*   adj_row  = (const int*)d_in[1];
    const int*   adj_col  = (const int*)d_in[2];
    const float* adj_vals = (const float*)d_in[3];
    const float* W0 = (const float*)d_in[4];
    const float* Wh[5] = {(const float*)d_in[5], (const float*)d_in[6], (const float*)d_in[7],
                          (const float*)d_in[8], (const float*)d_in[9]};
    const float* W6 = (const float*)d_in[10];

    const int E = in_sizes[1];
    const int K = in_sizes[4] / 32;   // 512
    const int N = in_sizes[0] / K;    // 10000

    char* ws = (char*)d_ws;
    size_t off = 0;
    auto alloc = [&](size_t bytes) -> void* {
        void* p = ws + off;
        off = (off + bytes + 255) & ~(size_t)255;
        return p;
    };
    int*   nxt   = (int*)alloc((size_t)N * 4);
    int*   ell_c = (int*)alloc((size_t)N * CAP * 4);
    float* ell_v = (float*)alloc((size_t)N * CAP * 4);
    float* Ya    = (float*)alloc((size_t)N * 32 * 4);
    float* Yb    = (float*)alloc((size_t)N * 32 * 4);
    float* Y16   = (float*)alloc((size_t)N * 16 * 4);
    float* zbuf  = (float*)alloc((size_t)N * 16 * 4);

    const int gridE = (E + THREADS - 1) / THREADS;
    const int gridG = (N * 32 + THREADS - 1) / THREADS;
    const int gridWave = (N * 64 + THREADS - 1) / THREADS;   // one wave64 per row

    zero_kernel<<<(N + THREADS - 1) / THREADS, THREADS, 0, stream>>>(nxt, N);
    build_and_gemm0_kernel<<<gridE + gridG, THREADS, 0, stream>>>(
        adj_row, adj_col, adj_vals, nxt, ell_c, ell_v, E, features, W0, Ya, N, K, gridE);

    float* yin = Ya;
    float* yout = Yb;
    for (int l = 0; l < 5; ++l) {
        fused_spmm_gemm_kernel<32><<<gridWave, THREADS, 0, stream>>>(nxt, ell_c, ell_v, yin, Wh[l], yout, N);
        float* tmp = yin; yin = yout; yout = tmp;
    }
    fused_spmm_gemm_kernel<16><<<gridWave, THREADS, 0, stream>>>(nxt, ell_c, ell_v, yin, W6, Y16, N);
    spmm16_kernel<<<(N * 32 + THREADS - 1) / THREADS, THREADS, 0, stream>>>(nxt, ell_c, ell_v, Y16, zbuf, N);

    dim3 zg((N + 1023) / 1024, (N + 31) / 32);
    zzt_kernel<<<zg, THREADS, 0, stream>>>(zbuf, (float*)d_out, N);
}

// Round 14
// 238.453 us; speedup vs baseline: 1.0943x; 1.0943x over previous
//
#include <hip/hip_runtime.h>

#define THREADS 256
#define CAP 128

typedef float floatx4 __attribute__((ext_vector_type(4)));

static __device__ __forceinline__ unsigned short f2b(float x) {
    unsigned int u = __float_as_uint(x);
    u += 0x7FFFu + ((u >> 16) & 1u);          // round-to-nearest-even
    return (unsigned short)(u >> 16);
}
static __device__ __forceinline__ float b2f(unsigned short h) {
    return __uint_as_float(((unsigned int)h) << 16);
}

// ---------------- phase 0: zero row counters ----------------

__global__ void zero_kernel(int* __restrict__ p, int n) {
    int i = blockIdx.x * blockDim.x + threadIdx.x;
    if (i < n) p[i] = 0;
}

// ---------------- phase 1 (merged): ELL scatter  ||  gemm0 (fp32 in, bf16 out) ----------------

__global__ void build_and_gemm0_kernel(const int* __restrict__ row, const int* __restrict__ col,
                                       const float* __restrict__ val, int* __restrict__ nxt,
                                       int* __restrict__ ell_c, float* __restrict__ ell_v, int E,
                                       const float* __restrict__ X, const float* __restrict__ W0,
                                       unsigned short* __restrict__ Y, int n, int K, int gridE) {
    if ((int)blockIdx.x < gridE) {
        int e = blockIdx.x * THREADS + threadIdx.x;
        if (e < E) {
            int r = row[e];
            int p = atomicAdd(&nxt[r], 1);
            if (p < CAP) {
                ell_c[r * CAP + p] = col[e];
                ell_v[r * CAP + p] = val[e];
            }
        }
    } else {
        int idx = (blockIdx.x - gridE) * THREADS + threadIdx.x;
        int r = idx >> 5;
        int f = idx & 31;
        if (r >= n) return;
        const float* xr = X + (size_t)r * K;
        float acc = 0.f;
        for (int k = 0; k < K; k += 4) {
            floatx4 x = *reinterpret_cast<const floatx4*>(xr + k);
            acc = fmaf(x.x, W0[(k + 0) * 32 + f], acc);
            acc = fmaf(x.y, W0[(k + 1) * 32 + f], acc);
            acc = fmaf(x.z, W0[(k + 2) * 32 + f], acc);
            acc = fmaf(x.w, W0[(k + 3) * 32 + f], acc);
        }
        Y[r * 32 + f] = f2b(acc);
    }
}

// ---------------- fused SpMM(+relu) + 32xFOUT GEMM  (bf16 activations) ----------------
// 32 lanes/row, 8-wide gather ILP. bf16 rows: one 64B line per gather (was 2x128B).

template <int FOUT>
__global__ void fused_spmm_gemm_kernel(const int* __restrict__ nxt, const int* __restrict__ ell_c,
                                       const float* __restrict__ ell_v,
                                       const unsigned short* __restrict__ Yin,
                                       const float* __restrict__ W,
                                       unsigned short* __restrict__ Yout, int n) {
    __shared__ float w[32 * FOUT];
    const int t = threadIdx.x;
    for (int i = t; i < 32 * FOUT; i += THREADS) w[i] = W[i];
    __syncthreads();

    int g = (blockIdx.x * THREADS + t) >> 5;
    if (g >= n) return;
    int f = t & 31;
    int deg = min(nxt[g], CAP);
    int base = g * CAP;
    float acc = 0.f;
    int i = 0;
    for (; i + 8 <= deg; i += 8) {
        int4    cc0 = *reinterpret_cast<const int4*>(ell_c + base + i);
        int4    cc1 = *reinterpret_cast<const int4*>(ell_c + base + i + 4);
        floatx4 vv0 = *reinterpret_cast<const floatx4*>(ell_v + base + i);
        floatx4 vv1 = *reinterpret_cast<const floatx4*>(ell_v + base + i + 4);
        float y0 = b2f(Yin[(size_t)cc0.x * 32 + f]);
        float y1 = b2f(Yin[(size_t)cc0.y * 32 + f]);
        float y2 = b2f(Yin[(size_t)cc0.z * 32 + f]);
        float y3 = b2f(Yin[(size_t)cc0.w * 32 + f]);
        float y4 = b2f(Yin[(size_t)cc1.x * 32 + f]);
        float y5 = b2f(Yin[(size_t)cc1.y * 32 + f]);
        float y6 = b2f(Yin[(size_t)cc1.z * 32 + f]);
        float y7 = b2f(Yin[(size_t)cc1.w * 32 + f]);
        acc = fmaf(vv0.x, y0, acc);
        acc = fmaf(vv0.y, y1, acc);
        acc = fmaf(vv0.z, y2, acc);
        acc = fmaf(vv0.w, y3, acc);
        acc = fmaf(vv1.x, y4, acc);
        acc = fmaf(vv1.y, y5, acc);
        acc = fmaf(vv1.z, y6, acc);
        acc = fmaf(vv1.w, y7, acc);
    }
    for (; i + 4 <= deg; i += 4) {
        int4    cc = *reinterpret_cast<const int4*>(ell_c + base + i);
        floatx4 vv = *reinterpret_cast<const floatx4*>(ell_v + base + i);
        acc = fmaf(vv.x, b2f(Yin[(size_t)cc.x * 32 + f]), acc);
        acc = fmaf(vv.y, b2f(Yin[(size_t)cc.y * 32 + f]), acc);
        acc = fmaf(vv.z, b2f(Yin[(size_t)cc.z * 32 + f]), acc);
        acc = fmaf(vv.w, b2f(Yin[(size_t)cc.w * 32 + f]), acc);
    }
    for (; i < deg; ++i)
        acc = fmaf(ell_v[base + i], b2f(Yin[(size_t)ell_c[base + i] * 32 + f]), acc);
    float h = fmaxf(acc, 0.f);

    const int fo = f & (FOUT - 1);
    float y = 0.f;
#pragma unroll
    for (int k = 0; k < 32; ++k)
        y = fmaf(__shfl(h, k, 32), w[k * FOUT + fo], y);
    if (f < FOUT) Yout[(size_t)g * FOUT + f] = f2b(y);
}

// final z = A @ Y16 (no relu); 16 lanes/row, bf16 in, fp32 out
__global__ void spmm16_kernel(const int* __restrict__ nxt, const int* __restrict__ ell_c,
                              const float* __restrict__ ell_v,
                              const unsigned short* __restrict__ Yin,
                              float* __restrict__ Z, int n) {
    int g = (blockIdx.x * blockDim.x + threadIdx.x) >> 4;
    if (g >= n) return;
    int f = threadIdx.x & 15;
    int deg = min(nxt[g], CAP);
    int base = g * CAP;
    float acc = 0.f;
    int i = 0;
    for (; i + 8 <= deg; i += 8) {
        int4    cc0 = *reinterpret_cast<const int4*>(ell_c + base + i);
        int4    cc1 = *reinterpret_cast<const int4*>(ell_c + base + i + 4);
        floatx4 vv0 = *reinterpret_cast<const floatx4*>(ell_v + base + i);
        floatx4 vv1 = *reinterpret_cast<const floatx4*>(ell_v + base + i + 4);
        acc = fmaf(vv0.x, b2f(Yin[(size_t)cc0.x * 16 + f]), acc);
        acc = fmaf(vv0.y, b2f(Yin[(size_t)cc0.y * 16 + f]), acc);
        acc = fmaf(vv0.z, b2f(Yin[(size_t)cc0.z * 16 + f]), acc);
        acc = fmaf(vv0.w, b2f(Yin[(size_t)cc0.w * 16 + f]), acc);
        acc = fmaf(vv1.x, b2f(Yin[(size_t)cc1.x * 16 + f]), acc);
        acc = fmaf(vv1.y, b2f(Yin[(size_t)cc1.y * 16 + f]), acc);
        acc = fmaf(vv1.z, b2f(Yin[(size_t)cc1.z * 16 + f]), acc);
        acc = fmaf(vv1.w, b2f(Yin[(size_t)cc1.w * 16 + f]), acc);
    }
    for (; i + 4 <= deg; i += 4) {
        int4    cc = *reinterpret_cast<const int4*>(ell_c + base + i);
        floatx4 vv = *reinterpret_cast<const floatx4*>(ell_v + base + i);
        acc = fmaf(vv.x, b2f(Yin[(size_t)cc.x * 16 + f]), acc);
        acc = fmaf(vv.y, b2f(Yin[(size_t)cc.y * 16 + f]), acc);
        acc = fmaf(vv.z, b2f(Yin[(size_t)cc.z * 16 + f]), acc);
        acc = fmaf(vv.w, b2f(Yin[(size_t)cc.w * 16 + f]), acc);
    }
    for (; i < deg; ++i)
        acc = fmaf(ell_v[base + i], b2f(Yin[(size_t)ell_c[base + i] * 16 + f]), acc);
    Z[(size_t)g * 16 + f] = acc;
}

// ---------------- z @ z^T (fp32; nt stores proven -18us) ----------------

__global__ void zzt_kernel(const float* __restrict__ z, float* __restrict__ out, int n) {
    __shared__ float zi[32][16];
    const int t = threadIdx.x;
    const int bi = blockIdx.y * 32;
    for (int i = t; i < 512; i += THREADS) {
        int r = i >> 4, c = i & 15;
        zi[r][c] = (bi + r < n) ? z[(size_t)(bi + r) * 16 + c] : 0.f;
    }
    __syncthreads();
    int j0 = blockIdx.x * 1024 + t * 4;
    if (j0 >= n) return;
    float zj[4][16];
#pragma unroll
    for (int jj = 0; jj < 4; ++jj) {
#pragma unroll
        for (int k = 0; k < 16; k += 4) {
            floatx4 v = *reinterpret_cast<const floatx4*>(z + (size_t)(j0 + jj) * 16 + k);
            zj[jj][k] = v.x; zj[jj][k + 1] = v.y; zj[jj][k + 2] = v.z; zj[jj][k + 3] = v.w;
        }
    }
#pragma unroll 4
    for (int i = 0; i < 32; ++i) {
        if (bi + i >= n) break;
        floatx4 o = {0.f, 0.f, 0.f, 0.f};
#pragma unroll
        for (int k = 0; k < 16; ++k) {
            float a = zi[i][k];
            o.x = fmaf(a, zj[0][k], o.x);
            o.y = fmaf(a, zj[1][k], o.y);
            o.z = fmaf(a, zj[2][k], o.z);
            o.w = fmaf(a, zj[3][k], o.w);
        }
        __builtin_nontemporal_store(o, reinterpret_cast<floatx4*>(out + (size_t)(bi + i) * n + j0));
    }
}

// ---------------- launch ----------------

extern "C" void kernel_launch(void* const* d_in, const int* in_sizes, int n_in,
                              void* d_out, int out_size, void* d_ws, size_t ws_size,
                              hipStream_t stream) {
    const float* features = (const float*)d_in[0];
    const int*   adj_row  = (const int*)d_in[1];
    const int*   adj_col  = (const int*)d_in[2];
    const float* adj_vals = (const float*)d_in[3];
    const float* W0 = (const float*)d_in[4];
    const float* Wh[5] = {(const float*)d_in[5], (const float*)d_in[6], (const float*)d_in[7],
                          (const float*)d_in[8], (const float*)d_in[9]};
    const float* W6 = (const float*)d_in[10];

    const int E = in_sizes[1];
    const int K = in_sizes[4] / 32;   // 512
    const int N = in_sizes[0] / K;    // 10000

    char* ws = (char*)d_ws;
    size_t off = 0;
    auto alloc = [&](size_t bytes) -> void* {
        void* p = ws + off;
        off = (off + bytes + 255) & ~(size_t)255;
        return p;
    };
    int*            nxt   = (int*)alloc((size_t)N * 4);
    int*            ell_c = (int*)alloc((size_t)N * CAP * 4);
    float*          ell_v = (float*)alloc((size_t)N * CAP * 4);
    unsigned short* Ya    = (unsigned short*)alloc((size_t)N * 32 * 2);
    unsigned short* Yb    = (unsigned short*)alloc((size_t)N * 32 * 2);
    unsigned short* Y16   = (unsigned short*)alloc((size_t)N * 16 * 2);
    float*          zbuf  = (float*)alloc((size_t)N * 16 * 4);

    const int gridE = (E + THREADS - 1) / THREADS;
    const int gridG = (N * 32 + THREADS - 1) / THREADS;
    const int gridRow = gridG;

    zero_kernel<<<(N + THREADS - 1) / THREADS, THREADS, 0, stream>>>(nxt, N);
    build_and_gemm0_kernel<<<gridE + gridG, THREADS, 0, stream>>>(
        adj_row, adj_col, adj_vals, nxt, ell_c, ell_v, E, features, W0, Ya, N, K, gridE);

    unsigned short* yin = Ya;
    unsigned short* yout = Yb;
    for (int l = 0; l < 5; ++l) {
        fused_spmm_gemm_kernel<32><<<gridRow, THREADS, 0, stream>>>(nxt, ell_c, ell_v, yin, Wh[l], yout, N);
        unsigned short* tmp = yin; yin = yout; yout = tmp;
    }
    fused_spmm_gemm_kernel<16><<<gridRow, THREADS, 0, stream>>>(nxt, ell_c, ell_v, yin, W6, Y16, N);
    spmm16_kernel<<<(N * 16 + THREADS - 1) / THREADS, THREADS, 0, stream>>>(nxt, ell_c, ell_v, Y16, zbuf, N);

    dim3 zg((N + 1023) / 1024, (N + 31) / 32);
    zzt_kernel<<<zg, THREADS, 0, stream>>>(zbuf, (float*)d_out, N);
}